// Round 11
// baseline (137.384 us; speedup 1.0000x reference)
//
#include <hip/hip_runtime.h>
#include <stdint.h>

// minerva2: echo = (F̂ Ê^T)^3 @ V, intensity = rowsum((F̂ Ê^T)^3)
// R11 = R10 (counted-vmcnt 4x8KB slab pipeline, swapped QK^T, in-reg PV) +
//  (a) chunk swizzle on slab (both-sides): fixes R10's 8-way bank conflict
//  (b) qA halved to [2][4], reloaded per K-half -> ~32 fewer live VGPRs
//      (target 3 blocks/CU instead of 2)

typedef unsigned short u16;
typedef __bf16 bf16x8 __attribute__((ext_vector_type(8)));
typedef float f32x4 __attribute__((ext_vector_type(4)));
typedef unsigned short u16x4 __attribute__((ext_vector_type(4)));

#define NQ 8192
#define ND 16384
#define NH 256
#define NC 28
#define DCHUNK 1024
#define NDT 8        // 128-row D-tiles per chunk
#define NSLOT 16     // partial slots = 16 D-chunks

#define VM12 asm volatile("s_waitcnt vmcnt(12)" ::: "memory")
#define VM4  asm volatile("s_waitcnt vmcnt(4)" ::: "memory")
#define VM2  asm volatile("s_waitcnt vmcnt(2)" ::: "memory")
#define VM0  asm volatile("s_waitcnt vmcnt(0)" ::: "memory")
#define SBAR { __builtin_amdgcn_s_barrier(); asm volatile("" ::: "memory"); }

__device__ __forceinline__ u16 f2bf(float f) {
  unsigned u = __builtin_bit_cast(unsigned, f);
  u += 0x7fffu + ((u >> 16) & 1u);   // RNE
  return (u16)(u >> 16);
}

__device__ __forceinline__ unsigned cvtpk(float lo, float hi) {
  unsigned r;
  asm("v_cvt_pk_bf16_f32 %0, %1, %2" : "=v"(r) : "v"(lo), "v"(hi));
  return r;  // low16 = bf16(lo), high16 = bf16(hi)  (RNE)
}

// After: x = [x.r0, x.r2, y.r0, y.r2] (by 16-lane row), y = [x.r1, x.r3, y.r1, y.r3]
__device__ __forceinline__ void swap2(unsigned& x, unsigned& y) {
  asm("v_permlane32_swap_b32 %0, %1" : "+v"(x), "+v"(y));  // x.r23 <-> y.r01
  asm("v_permlane16_swap_b32 %0, %1" : "+v"(x), "+v"(y));  // x.r1<->y.r0, x.r3<->y.r2
}

__device__ __forceinline__ void gload16(const void* g, void* l) {
  // async global->LDS, 16B/lane; LDS dest = wave-uniform base + lane*16
  __builtin_amdgcn_global_load_lds(
      (__attribute__((address_space(1))) void*)g,
      (__attribute__((address_space(3))) void*)l, 16, 0, 0);
}

// ---------------- normalize rows of [rows][256] f32 -> bf16 ----------------
__global__ __launch_bounds__(256) void norm_kernel(const float* __restrict__ in,
                                                   u16* __restrict__ out, int rows) {
  const int wid = threadIdx.x >> 6, lane = threadIdx.x & 63;
  const int row = blockIdx.x * 4 + wid;
  if (row >= rows) return;
  const float4* p = (const float4*)(in + (size_t)row * NH);
  float4 v = p[lane];
  float ss = v.x * v.x + v.y * v.y + v.z * v.z + v.w * v.w;
#pragma unroll
  for (int m = 1; m <= 32; m <<= 1) ss += __shfl_xor(ss, m, 64);
  const float sc = 1.0f / fmaxf(sqrtf(ss), 1e-12f);  // matches F.normalize eps
  u16x4 o;
  o.x = f2bf(v.x * sc); o.y = f2bf(v.y * sc);
  o.z = f2bf(v.z * sc); o.w = f2bf(v.w * sc);
  *(u16x4*)(out + (size_t)row * NH + lane * 4) = o;
}

// ---- V [16384][28] f32 -> Vt [32][16384] bf16; col 28 = 1.0 (intensity) ---
__global__ __launch_bounds__(256) void vt_kernel(const float* __restrict__ V,
                                                 u16* __restrict__ Vt) {
  const int d = blockIdx.x * 256 + threadIdx.x;  // 16384
#pragma unroll
  for (int c = 0; c < NC; ++c) Vt[(size_t)c * ND + d] = f2bf(V[(size_t)d * NC + c]);
  Vt[(size_t)28 * ND + d] = 0x3F80;  // bf16 1.0 -> echo col 28 == intensity
  Vt[(size_t)29 * ND + d] = 0;
  Vt[(size_t)30 * ND + d] = 0;
  Vt[(size_t)31 * ND + d] = 0;
}

// ---------------- fused main kernel ----------------------------------------
// grid 1024: dch = bid&15 (XCD-local), ntile = bid>>4. 4 waves, 1x4 over q.
// LDS 32KB = 4 slab bufs [128d][32k] bf16 (8KB). Slab g -> buf g&3.
// Chunk swizzle: stored chunk p at row R holds logical chunk p ^ ((R>>1)&3).
// Pipeline: issue stage(g+2), counted vmcnt, raw s_barrier per step.
__global__ __launch_bounds__(256, 2) void fused_kernel(
    const u16* __restrict__ Qn, const u16* __restrict__ Kn,
    const u16* __restrict__ Vt, float* __restrict__ ep) {
  __shared__ alignas(16) char smem[32768];
  const int tid = threadIdx.x;
  const int wid = tid >> 6;
  const int lane = tid & 63;
  const int l16 = lane & 15;
  const int lg = lane >> 4;
  const int dch = blockIdx.x & 15;
  const int ntile = blockIdx.x >> 4;
  const int rowbase = ntile * 128 + wid * 32;

  // ---- Q fragments, HALF of H at a time, in registers (MFMA B-operand) ----
  bf16x8 qA[2][4];
  auto loadQ = [&](int h) {
#pragma unroll
    for (int mb = 0; mb < 2; ++mb)
#pragma unroll
      for (int k = 0; k < 4; ++k)
        qA[mb][k] = *(const bf16x8*)(Qn + (size_t)(rowbase + mb * 16 + l16) * NH +
                                     (h * 4 + k) * 32 + lg * 8);
  };

  f32x4 eacc[2][2];
#pragma unroll
  for (int mb = 0; mb < 2; ++mb) {
    eacc[mb][0] = f32x4{0.f, 0.f, 0.f, 0.f};
    eacc[mb][1] = f32x4{0.f, 0.f, 0.f, 0.f};
  }
  f32x4 sacc[2][8];

  const u16* kc = Kn + (size_t)dch * DCHUNK * NH;
  // staging source base: row = tid>>2 (+64 for r=1), stored chunk pos = tid&3
  // holds logical chunk (tid&3) ^ ((row>>1)&3) = (tid&3) ^ ((tid>>3)&3)
  const u16* kb = kc + (size_t)(tid >> 2) * NH + ((tid & 3) ^ ((tid >> 3) & 3)) * 8;

  // stage slab -> buf: [128d][32k] bf16, linear LDS dest (chunk-swizzled source)
  auto stage = [&](int buf, const u16* src0) {
#pragma unroll
    for (int r = 0; r < 2; ++r)
      gload16(src0 + (size_t)r * 64 * NH,
              smem + buf * 8192 + r * 4096 + wid * 1024);
  };

  const int rsw = (l16 >> 1) & 3;  // (row>>1)&3 for row = nb*16 + l16

  // prologue: Q half0, slabs 0,1 of tile 0
  loadQ(0);
  stage(0, kb);
  stage(1, kb + 32);

  for (int t = 0; t < NDT; ++t) {
    const size_t toff = (size_t)t * 128 * NH;
#pragma unroll
    for (int mb = 0; mb < 2; ++mb)
#pragma unroll
      for (int nb = 0; nb < 8; ++nb) sacc[mb][nb] = f32x4{0.f, 0.f, 0.f, 0.f};

#pragma unroll
    for (int i = 0; i < 8; ++i) {
      // issue stage of slab (8t + i + 2), two slabs ahead
      if (i < 6) stage((i + 2) & 3, kb + toff + (i + 2) * 32);
      else if (t < NDT - 1) stage((i + 2) & 3, kb + toff + 128 * NH + (i - 6) * 32);

      // counted wait for stage(i); qA reloads sit in the window at steps 0,1,4,5
      if (i == 0 || i == 1) { if (t == 0) { VM4; } else { VM12; } }
      else if (i == 2 || i == 3) { VM4; }
      else if (i == 4 || i == 5) { VM12; }
      else if (i == 6) { if (t < NDT - 1) { VM4; } else { VM2; } }
      else { if (t < NDT - 1) { VM4; } else { VM0; } }
      SBAR;

      // compute slab i: 8 swizzled b128 reads + 16 MFMA (swapped: D = S^T)
      const char* kbuf = smem + (i & 3) * 8192;
      bf16x8 B[8];
#pragma unroll
      for (int nb = 0; nb < 8; ++nb)
        B[nb] = *(const bf16x8*)(kbuf + (nb * 16 + l16) * 64 + ((lg ^ rsw) << 4));
#pragma unroll
      for (int mb = 0; mb < 2; ++mb)
#pragma unroll
        for (int nb = 0; nb < 8; ++nb)
          sacc[mb][nb] = __builtin_amdgcn_mfma_f32_16x16x32_bf16(
              B[nb], qA[mb][i & 3], sacc[mb][nb], 0, 0, 0);

      // after last half0 consumer: fetch half1 (hidden under step 4's stage+bar)
      if (i == 3) loadQ(1);
    }

    // ---- cube (fp32) -> bf16 pack -> permlane transpose -> PV MFMA ----
    // sacc[mb][nb]: q = l16, d(in tile) = nb*16 + lg*4 + r.
    const int dbase = dch * DCHUNK + t * 128;
#pragma unroll
    for (int mb = 0; mb < 2; ++mb) {
#pragma unroll
      for (int tg = 0; tg < 4; ++tg) {
        f32x4 sx = sacc[mb][2 * tg];
        f32x4 sy = sacc[mb][2 * tg + 1];
        f32x4 cx = sx * sx * sx;
        f32x4 cy = sy * sy * sy;
        unsigned x0 = cvtpk(cx[0], cx[1]);  // d = 4lg+0,1   (nb = 2tg)
        unsigned x1 = cvtpk(cx[2], cx[3]);  // d = 4lg+2,3
        unsigned y0 = cvtpk(cy[0], cy[1]);  // same, nb = 2tg+1
        unsigned y1 = cvtpk(cy[2], cy[3]);
        swap2(x0, y0);  // x0 -> a0 (k 8g+0,1), y0 -> a2 (k 8g+4,5)
        swap2(x1, y1);  // x1 -> a1 (k 8g+2,3), y1 -> a3 (k 8g+6,7)
        const int4 ai = {(int)x0, (int)x1, (int)y0, (int)y1};
        const bf16x8 aA = __builtin_bit_cast(bf16x8, ai);
#pragma unroll
        for (int cn = 0; cn < 2; ++cn) {
          const bf16x8 vBf = *(const bf16x8*)(Vt + (size_t)(cn * 16 + l16) * ND +
                                              dbase + tg * 32 + lg * 8);
          eacc[mb][cn] = __builtin_amdgcn_mfma_f32_16x16x32_bf16(
              aA, vBf, eacc[mb][cn], 0, 0, 0);
        }
      }
    }

    // fetch next tile's Q half0 (hidden under PV tail / next step 0 stage+bar)
    if (t < NDT - 1) loadQ(0);
  }

  // ---- epilogue: write partials (slot = dch) ----
#pragma unroll
  for (int mb = 0; mb < 2; ++mb)
#pragma unroll
    for (int cn = 0; cn < 2; ++cn)
#pragma unroll
      for (int r = 0; r < 4; ++r) {
        const int row = rowbase + mb * 16 + lg * 4 + r;
        ep[((size_t)dch * NQ + row) * 32 + cn * 16 + l16] = eacc[mb][cn][r];
      }
}

// ---------------- reduce 16 partial slots -> d_out -------------------------
__global__ __launch_bounds__(256) void reduce_kernel(const float* __restrict__ ep,
                                                     float* __restrict__ out) {
  const int g = blockIdx.x * 256 + threadIdx.x;  // 8192*32
  const int q = g >> 5, c = g & 31;
  if (c < NC) {
    float s = 0.f;
#pragma unroll
    for (int k = 0; k < NSLOT; ++k) s += ep[((size_t)k * NQ + q) * 32 + c];
    out[(size_t)q * NC + c] = s;
  } else if (c == NC) {  // ones-column == intensity
    float s = 0.f;
#pragma unroll
    for (int k = 0; k < NSLOT; ++k) s += ep[((size_t)k * NQ + q) * 32 + NC];
    out[(size_t)NQ * NC + q] = s;
  }
}

extern "C" void kernel_launch(void* const* d_in, const int* in_sizes, int n_in,
                              void* d_out, int out_size, void* d_ws, size_t ws_size,
                              hipStream_t stream) {
  const float* feat = (const float*)d_in[0];  // [8192][256]
  const float* exf  = (const float*)d_in[1];  // [16384][256]
  const float* exc  = (const float*)d_in[2];  // [16384][28]
  float* out = (float*)d_out;
  char* ws = (char*)d_ws;
  // ws layout: qn 4MB | kn 8MB | vt 1MB | ep 16MB  (~29MB)
  u16* qn = (u16*)ws;
  u16* kn = (u16*)(ws + 4194304);
  u16* vt = (u16*)(ws + 12582912);
  float* ep = (float*)(ws + 13631488);

  norm_kernel<<<dim3(NQ / 4), dim3(256), 0, stream>>>(feat, qn, NQ);
  norm_kernel<<<dim3(ND / 4), dim3(256), 0, stream>>>(exf, kn, ND);
  vt_kernel<<<dim3(ND / 256), dim3(256), 0, stream>>>(exc, vt);
  fused_kernel<<<dim3(1024), dim3(256), 0, stream>>>(qn, kn, vt, ep);
  reduce_kernel<<<dim3(NQ * 32 / 256), dim3(256), 0, stream>>>(ep, out);
}

// Round 12
// 100.915 us; speedup vs baseline: 1.3614x; 1.3614x over previous
//
#include <hip/hip_runtime.h>
#include <stdint.h>

// minerva2: echo = (F̂ Ê^T)^3 @ V, intensity = rowsum((F̂ Ê^T)^3)
// R12 = R10 counted-vmcnt 4x8KB slab pipeline (full qA[2][8] resident)
//     + R11 both-sides chunk swizzle (verified 0-conflict)
//     + T5 setprio around QK MFMA cluster.
// Swapped QK^T (S^T) + in-register cube/cvt_pk/permlane transpose -> PV.

typedef unsigned short u16;
typedef __bf16 bf16x8 __attribute__((ext_vector_type(8)));
typedef float f32x4 __attribute__((ext_vector_type(4)));
typedef unsigned short u16x4 __attribute__((ext_vector_type(4)));

#define NQ 8192
#define ND 16384
#define NH 256
#define NC 28
#define DCHUNK 1024
#define NDT 8        // 128-row D-tiles per chunk
#define NSLOT 16     // partial slots = 16 D-chunks

#define VM4 asm volatile("s_waitcnt vmcnt(4)" ::: "memory")
#define VM2 asm volatile("s_waitcnt vmcnt(2)" ::: "memory")
#define VM0 asm volatile("s_waitcnt vmcnt(0)" ::: "memory")
#define SBAR { __builtin_amdgcn_s_barrier(); asm volatile("" ::: "memory"); }

__device__ __forceinline__ u16 f2bf(float f) {
  unsigned u = __builtin_bit_cast(unsigned, f);
  u += 0x7fffu + ((u >> 16) & 1u);   // RNE
  return (u16)(u >> 16);
}

__device__ __forceinline__ unsigned cvtpk(float lo, float hi) {
  unsigned r;
  asm("v_cvt_pk_bf16_f32 %0, %1, %2" : "=v"(r) : "v"(lo), "v"(hi));
  return r;  // low16 = bf16(lo), high16 = bf16(hi)  (RNE)
}

// After: x = [x.r0, x.r2, y.r0, y.r2] (by 16-lane row), y = [x.r1, x.r3, y.r1, y.r3]
__device__ __forceinline__ void swap2(unsigned& x, unsigned& y) {
  asm("v_permlane32_swap_b32 %0, %1" : "+v"(x), "+v"(y));  // x.r23 <-> y.r01
  asm("v_permlane16_swap_b32 %0, %1" : "+v"(x), "+v"(y));  // x.r1<->y.r0, x.r3<->y.r2
}

__device__ __forceinline__ void gload16(const void* g, void* l) {
  // async global->LDS, 16B/lane; LDS dest = wave-uniform base + lane*16
  __builtin_amdgcn_global_load_lds(
      (__attribute__((address_space(1))) void*)g,
      (__attribute__((address_space(3))) void*)l, 16, 0, 0);
}

// ---------------- normalize rows of [rows][256] f32 -> bf16 ----------------
__global__ __launch_bounds__(256) void norm_kernel(const float* __restrict__ in,
                                                   u16* __restrict__ out, int rows) {
  const int wid = threadIdx.x >> 6, lane = threadIdx.x & 63;
  const int row = blockIdx.x * 4 + wid;
  if (row >= rows) return;
  const float4* p = (const float4*)(in + (size_t)row * NH);
  float4 v = p[lane];
  float ss = v.x * v.x + v.y * v.y + v.z * v.z + v.w * v.w;
#pragma unroll
  for (int m = 1; m <= 32; m <<= 1) ss += __shfl_xor(ss, m, 64);
  const float sc = 1.0f / fmaxf(sqrtf(ss), 1e-12f);  // matches F.normalize eps
  u16x4 o;
  o.x = f2bf(v.x * sc); o.y = f2bf(v.y * sc);
  o.z = f2bf(v.z * sc); o.w = f2bf(v.w * sc);
  *(u16x4*)(out + (size_t)row * NH + lane * 4) = o;
}

// ---- V [16384][28] f32 -> Vt [32][16384] bf16; col 28 = 1.0 (intensity) ---
__global__ __launch_bounds__(256) void vt_kernel(const float* __restrict__ V,
                                                 u16* __restrict__ Vt) {
  const int d = blockIdx.x * 256 + threadIdx.x;  // 16384
#pragma unroll
  for (int c = 0; c < NC; ++c) Vt[(size_t)c * ND + d] = f2bf(V[(size_t)d * NC + c]);
  Vt[(size_t)28 * ND + d] = 0x3F80;  // bf16 1.0 -> echo col 28 == intensity
  Vt[(size_t)29 * ND + d] = 0;
  Vt[(size_t)30 * ND + d] = 0;
  Vt[(size_t)31 * ND + d] = 0;
}

// ---------------- fused main kernel ----------------------------------------
// grid 1024: dch = bid&15 (XCD-local), ntile = bid>>4. 4 waves, 1x4 over q:
// wave w owns q-rows [ntile*128+w*32, +32) x 128 d-cols per tile.
// Q in registers. LDS 32KB = 4 slab bufs [128d][32k] bf16 (8KB each).
// Chunk swizzle: stored chunk p at row R holds logical chunk p ^ ((R>>1)&3).
// Pipeline: issue stage(g+2), counted vmcnt (VM4 steady), raw s_barrier.
__global__ __launch_bounds__(256, 2) void fused_kernel(
    const u16* __restrict__ Qn, const u16* __restrict__ Kn,
    const u16* __restrict__ Vt, float* __restrict__ ep) {
  __shared__ alignas(16) char smem[32768];
  const int tid = threadIdx.x;
  const int wid = tid >> 6;
  const int lane = tid & 63;
  const int l16 = lane & 15;
  const int lg = lane >> 4;
  const int dch = blockIdx.x & 15;
  const int ntile = blockIdx.x >> 4;
  const int rowbase = ntile * 128 + wid * 32;

  // ---- Q fragments, all H, in registers (MFMA B-operand) ----
  bf16x8 qA[2][8];
#pragma unroll
  for (int mb = 0; mb < 2; ++mb)
#pragma unroll
    for (int ks = 0; ks < 8; ++ks)
      qA[mb][ks] = *(const bf16x8*)(Qn + (size_t)(rowbase + mb * 16 + l16) * NH +
                                    ks * 32 + lg * 8);

  f32x4 eacc[2][2];
#pragma unroll
  for (int mb = 0; mb < 2; ++mb) {
    eacc[mb][0] = f32x4{0.f, 0.f, 0.f, 0.f};
    eacc[mb][1] = f32x4{0.f, 0.f, 0.f, 0.f};
  }
  f32x4 sacc[2][8];

  const u16* kc = Kn + (size_t)dch * DCHUNK * NH;
  // staging source base: row = tid>>2 (+64 for r=1), stored chunk pos = tid&3
  // holds logical chunk (tid&3) ^ ((row>>1)&3) = (tid&3) ^ ((tid>>3)&3)
  const u16* kb = kc + (size_t)(tid >> 2) * NH + ((tid & 3) ^ ((tid >> 3) & 3)) * 8;

  // stage slab -> buf: [128d][32k] bf16, linear LDS dest (chunk-swizzled source)
  auto stage = [&](int buf, const u16* src0) {
#pragma unroll
    for (int r = 0; r < 2; ++r)
      gload16(src0 + (size_t)r * 64 * NH,
              smem + buf * 8192 + r * 4096 + wid * 1024);
  };

  const int rsw = (l16 >> 1) & 3;  // (row>>1)&3 for row = nb*16 + l16

  // prologue: slabs 0,1 of tile 0
  stage(0, kb);
  stage(1, kb + 32);

  for (int t = 0; t < NDT; ++t) {
    const size_t toff = (size_t)t * 128 * NH;
#pragma unroll
    for (int mb = 0; mb < 2; ++mb)
#pragma unroll
      for (int nb = 0; nb < 8; ++nb) sacc[mb][nb] = f32x4{0.f, 0.f, 0.f, 0.f};

#pragma unroll
    for (int i = 0; i < 8; ++i) {
      // issue stage of slab (8t + i + 2), two slabs ahead
      if (i < 6) {
        stage((i + 2) & 3, kb + toff + (i + 2) * 32);
        VM4;
      } else if (t < NDT - 1) {
        stage((i + 2) & 3, kb + toff + 128 * NH + (i - 6) * 32);
        VM4;
      } else if (i == 6) {
        VM2;
      } else {
        VM0;
      }
      SBAR;  // all waves waited their stage(i) -> slab i visible to everyone

      // compute slab i: 8 swizzled b128 reads + 16 MFMA (swapped: D = S^T)
      const char* kbuf = smem + (i & 3) * 8192;
      bf16x8 B[8];
#pragma unroll
      for (int nb = 0; nb < 8; ++nb)
        B[nb] = *(const bf16x8*)(kbuf + (nb * 16 + l16) * 64 + ((lg ^ rsw) << 4));
      __builtin_amdgcn_s_setprio(1);
#pragma unroll
      for (int mb = 0; mb < 2; ++mb)
#pragma unroll
        for (int nb = 0; nb < 8; ++nb)
          sacc[mb][nb] = __builtin_amdgcn_mfma_f32_16x16x32_bf16(
              B[nb], qA[mb][i], sacc[mb][nb], 0, 0, 0);
      __builtin_amdgcn_s_setprio(0);
    }

    // ---- cube (fp32) -> bf16 pack -> permlane transpose -> PV MFMA ----
    // sacc[mb][nb]: q = l16, d(in tile) = nb*16 + lg*4 + r.
    const int dbase = dch * DCHUNK + t * 128;
#pragma unroll
    for (int mb = 0; mb < 2; ++mb) {
#pragma unroll
      for (int tg = 0; tg < 4; ++tg) {
        f32x4 sx = sacc[mb][2 * tg];
        f32x4 sy = sacc[mb][2 * tg + 1];
        f32x4 cx = sx * sx * sx;
        f32x4 cy = sy * sy * sy;
        unsigned x0 = cvtpk(cx[0], cx[1]);  // d = 4lg+0,1   (nb = 2tg)
        unsigned x1 = cvtpk(cx[2], cx[3]);  // d = 4lg+2,3
        unsigned y0 = cvtpk(cy[0], cy[1]);  // same, nb = 2tg+1
        unsigned y1 = cvtpk(cy[2], cy[3]);
        swap2(x0, y0);  // x0 -> a0 (k 8g+0,1), y0 -> a2 (k 8g+4,5)
        swap2(x1, y1);  // x1 -> a1 (k 8g+2,3), y1 -> a3 (k 8g+6,7)
        const int4 ai = {(int)x0, (int)x1, (int)y0, (int)y1};
        const bf16x8 aA = __builtin_bit_cast(bf16x8, ai);
#pragma unroll
        for (int cn = 0; cn < 2; ++cn) {
          const bf16x8 vBf = *(const bf16x8*)(Vt + (size_t)(cn * 16 + l16) * ND +
                                              dbase + tg * 32 + lg * 8);
          eacc[mb][cn] = __builtin_amdgcn_mfma_f32_16x16x32_bf16(
              aA, vBf, eacc[mb][cn], 0, 0, 0);
        }
      }
    }
    // PV touches no LDS; slab bufs protected by the step barriers (distance-2 WAR)
  }

  // ---- epilogue: write partials (slot = dch) ----
#pragma unroll
  for (int mb = 0; mb < 2; ++mb)
#pragma unroll
    for (int cn = 0; cn < 2; ++cn)
#pragma unroll
      for (int r = 0; r < 4; ++r) {
        const int row = rowbase + mb * 16 + lg * 4 + r;
        ep[((size_t)dch * NQ + row) * 32 + cn * 16 + l16] = eacc[mb][cn][r];
      }
}

// ---------------- reduce 16 partial slots -> d_out -------------------------
__global__ __launch_bounds__(256) void reduce_kernel(const float* __restrict__ ep,
                                                     float* __restrict__ out) {
  const int g = blockIdx.x * 256 + threadIdx.x;  // 8192*32
  const int q = g >> 5, c = g & 31;
  if (c < NC) {
    float s = 0.f;
#pragma unroll
    for (int k = 0; k < NSLOT; ++k) s += ep[((size_t)k * NQ + q) * 32 + c];
    out[(size_t)q * NC + c] = s;
  } else if (c == NC) {  // ones-column == intensity
    float s = 0.f;
#pragma unroll
    for (int k = 0; k < NSLOT; ++k) s += ep[((size_t)k * NQ + q) * 32 + NC];
    out[(size_t)NQ * NC + q] = s;
  }
}

extern "C" void kernel_launch(void* const* d_in, const int* in_sizes, int n_in,
                              void* d_out, int out_size, void* d_ws, size_t ws_size,
                              hipStream_t stream) {
  const float* feat = (const float*)d_in[0];  // [8192][256]
  const float* exf  = (const float*)d_in[1];  // [16384][256]
  const float* exc  = (const float*)d_in[2];  // [16384][28]
  float* out = (float*)d_out;
  char* ws = (char*)d_ws;
  // ws layout: qn 4MB | kn 8MB | vt 1MB | ep 16MB  (~29MB)
  u16* qn = (u16*)ws;
  u16* kn = (u16*)(ws + 4194304);
  u16* vt = (u16*)(ws + 12582912);
  float* ep = (float*)(ws + 13631488);

  norm_kernel<<<dim3(NQ / 4), dim3(256), 0, stream>>>(feat, qn, NQ);
  norm_kernel<<<dim3(ND / 4), dim3(256), 0, stream>>>(exf, kn, ND);
  vt_kernel<<<dim3(ND / 256), dim3(256), 0, stream>>>(exc, vt);
  fused_kernel<<<dim3(1024), dim3(256), 0, stream>>>(qn, kn, vt, ep);
  reduce_kernel<<<dim3(NQ * 32 / 256), dim3(256), 0, stream>>>(ep, out);
}

// Round 13
// 98.816 us; speedup vs baseline: 1.3903x; 1.0212x over previous
//
#include <hip/hip_runtime.h>
#include <stdint.h>

// minerva2: echo = (F̂ Ê^T)^3 @ V, intensity = rowsum((F̂ Ê^T)^3)
// R13 = R7 skeleton (2-buf LDS, stage->compute->sync, swapped QK^T,
// in-reg cube/cvt_pk/permlane transpose PV) with 64-row D-tiles:
// sacc[2][4] (-32 VGPR) targeting 3 waves/SIMD residency.
// Slab = [64d][128k] 16KB, both-sides chunk swizzle (chunk ^ (row&7)).

typedef unsigned short u16;
typedef __bf16 bf16x8 __attribute__((ext_vector_type(8)));
typedef float f32x4 __attribute__((ext_vector_type(4)));
typedef unsigned short u16x4 __attribute__((ext_vector_type(4)));

#define NQ 8192
#define ND 16384
#define NH 256
#define NC 28
#define DCHUNK 1024
#define NDT 16       // 64-row D-tiles per chunk
#define NSLOT 16     // partial slots = 16 D-chunks

__device__ __forceinline__ u16 f2bf(float f) {
  unsigned u = __builtin_bit_cast(unsigned, f);
  u += 0x7fffu + ((u >> 16) & 1u);   // RNE
  return (u16)(u >> 16);
}

__device__ __forceinline__ unsigned cvtpk(float lo, float hi) {
  unsigned r;
  asm("v_cvt_pk_bf16_f32 %0, %1, %2" : "=v"(r) : "v"(lo), "v"(hi));
  return r;  // low16 = bf16(lo), high16 = bf16(hi)  (RNE)
}

// After: x = [x.r0, x.r2, y.r0, y.r2] (by 16-lane row), y = [x.r1, x.r3, y.r1, y.r3]
__device__ __forceinline__ void swap2(unsigned& x, unsigned& y) {
  asm("v_permlane32_swap_b32 %0, %1" : "+v"(x), "+v"(y));  // x.r23 <-> y.r01
  asm("v_permlane16_swap_b32 %0, %1" : "+v"(x), "+v"(y));  // x.r1<->y.r0, x.r3<->y.r2
}

__device__ __forceinline__ void gload16(const void* g, void* l) {
  // async global->LDS, 16B/lane; LDS dest = wave-uniform base + lane*16
  __builtin_amdgcn_global_load_lds(
      (__attribute__((address_space(1))) void*)g,
      (__attribute__((address_space(3))) void*)l, 16, 0, 0);
}

// ---------------- normalize rows of [rows][256] f32 -> bf16 ----------------
__global__ __launch_bounds__(256) void norm_kernel(const float* __restrict__ in,
                                                   u16* __restrict__ out, int rows) {
  const int wid = threadIdx.x >> 6, lane = threadIdx.x & 63;
  const int row = blockIdx.x * 4 + wid;
  if (row >= rows) return;
  const float4* p = (const float4*)(in + (size_t)row * NH);
  float4 v = p[lane];
  float ss = v.x * v.x + v.y * v.y + v.z * v.z + v.w * v.w;
#pragma unroll
  for (int m = 1; m <= 32; m <<= 1) ss += __shfl_xor(ss, m, 64);
  const float sc = 1.0f / fmaxf(sqrtf(ss), 1e-12f);  // matches F.normalize eps
  u16x4 o;
  o.x = f2bf(v.x * sc); o.y = f2bf(v.y * sc);
  o.z = f2bf(v.z * sc); o.w = f2bf(v.w * sc);
  *(u16x4*)(out + (size_t)row * NH + lane * 4) = o;
}

// ---- V [16384][28] f32 -> Vt [32][16384] bf16; col 28 = 1.0 (intensity) ---
__global__ __launch_bounds__(256) void vt_kernel(const float* __restrict__ V,
                                                 u16* __restrict__ Vt) {
  const int d = blockIdx.x * 256 + threadIdx.x;  // 16384
#pragma unroll
  for (int c = 0; c < NC; ++c) Vt[(size_t)c * ND + d] = f2bf(V[(size_t)d * NC + c]);
  Vt[(size_t)28 * ND + d] = 0x3F80;  // bf16 1.0 -> echo col 28 == intensity
  Vt[(size_t)29 * ND + d] = 0;
  Vt[(size_t)30 * ND + d] = 0;
  Vt[(size_t)31 * ND + d] = 0;
}

// ---------------- fused main kernel ----------------------------------------
// grid 1024: dch = bid&15 (XCD-local), ntile = bid>>4. 4 waves, 1x4 over q:
// wave w owns q-rows [ntile*128+w*32, +32) x 64 d-rows per tile.
// Q (all H) in registers. LDS 32KB = 2 bufs of [64d][128k] bf16 (16KB).
// Chunk swizzle: stored 16B-chunk p at row R holds logical chunk p ^ (R&7).
__global__ __launch_bounds__(256, 3) void fused_kernel(
    const u16* __restrict__ Qn, const u16* __restrict__ Kn,
    const u16* __restrict__ Vt, float* __restrict__ ep) {
  __shared__ alignas(16) char smem[32768];
  const int tid = threadIdx.x;
  const int wid = tid >> 6;
  const int lane = tid & 63;
  const int l16 = lane & 15;
  const int lg = lane >> 4;
  const int dch = blockIdx.x & 15;
  const int ntile = blockIdx.x >> 4;
  const int rowbase = ntile * 128 + wid * 32;

  // ---- Q fragments, all H, in registers (MFMA B-operand) ----
  bf16x8 qA[2][8];
#pragma unroll
  for (int mb = 0; mb < 2; ++mb)
#pragma unroll
    for (int ks = 0; ks < 8; ++ks)
      qA[mb][ks] = *(const bf16x8*)(Qn + (size_t)(rowbase + mb * 16 + l16) * NH +
                                    ks * 32 + lg * 8);

  f32x4 eacc[2][2];
#pragma unroll
  for (int mb = 0; mb < 2; ++mb) {
    eacc[mb][0] = f32x4{0.f, 0.f, 0.f, 0.f};
    eacc[mb][1] = f32x4{0.f, 0.f, 0.f, 0.f};
  }
  f32x4 sacc[2][4];

  const u16* kc = Kn + (size_t)dch * DCHUNK * NH;
  // staging source base: row = tid>>4 (0..15, +16/iter), stored chunk = tid&15
  // holds logical chunk (tid&15) ^ (row&7) = (tid&15) ^ ((tid>>4)&7)
  const u16* kb = kc + (size_t)(tid >> 4) * NH + ((tid & 15) ^ ((tid >> 4) & 7)) * 8;

  // stage slab -> buf: [64d][128k] bf16 (16KB), linear LDS dest,
  // chunk-swizzled global source. src0 = kb + tile/half offset.
  auto stage = [&](int buf, const u16* src0) {
#pragma unroll
    for (int r = 0; r < 4; ++r)
      gload16(src0 + (size_t)r * 16 * NH,
              smem + buf * 16384 + r * 4096 + wid * 1024);
  };

  // compute one staged half h (buf): 4 k2-steps of 32k, 8 MFMA each (D = S^T)
  auto compute = [&](int buf, int h) {
    const char* kbuf = smem + buf * 16384;
#pragma unroll
    for (int k2 = 0; k2 < 4; ++k2) {
      bf16x8 B[4];
#pragma unroll
      for (int nb = 0; nb < 4; ++nb)
        B[nb] = *(const bf16x8*)(kbuf + (nb * 16 + l16) * 256 +
                                 (((k2 * 4 + lg) ^ (l16 & 7)) << 4));
#pragma unroll
      for (int mb = 0; mb < 2; ++mb)
#pragma unroll
        for (int nb = 0; nb < 4; ++nb)
          sacc[mb][nb] = __builtin_amdgcn_mfma_f32_16x16x32_bf16(
              B[nb], qA[mb][h * 4 + k2], sacc[mb][nb], 0, 0, 0);
    }
  };

  // prologue: tile 0 half 0 -> buf 0
  stage(0, kb);
  __syncthreads();

  for (int t = 0; t < NDT; ++t) {
    const size_t toff = (size_t)t * 64 * NH;
#pragma unroll
    for (int mb = 0; mb < 2; ++mb)
#pragma unroll
      for (int nb = 0; nb < 4; ++nb) sacc[mb][nb] = f32x4{0.f, 0.f, 0.f, 0.f};

    // s0: stage half1 -> buf1, compute half0 (buf0)
    stage(1, kb + toff + 128);
    compute(0, 0);
    __syncthreads();
    // s1: stage next tile half0 -> buf0, compute half1 (buf1)
    if (t < NDT - 1) stage(0, kb + toff + 64 * NH);
    compute(1, 1);
    __syncthreads();

    // ---- cube (fp32) -> bf16 pack -> permlane transpose -> PV MFMA ----
    // sacc[mb][nb]: q = l16, d(in tile) = nb*16 + lg*4 + r.
    const int dbase = dch * DCHUNK + t * 64;
#pragma unroll
    for (int mb = 0; mb < 2; ++mb) {
#pragma unroll
      for (int tg = 0; tg < 2; ++tg) {
        f32x4 sx = sacc[mb][2 * tg];
        f32x4 sy = sacc[mb][2 * tg + 1];
        f32x4 cx = sx * sx * sx;
        f32x4 cy = sy * sy * sy;
        unsigned x0 = cvtpk(cx[0], cx[1]);  // d = 4lg+0,1   (nb = 2tg)
        unsigned x1 = cvtpk(cx[2], cx[3]);  // d = 4lg+2,3
        unsigned y0 = cvtpk(cy[0], cy[1]);  // same, nb = 2tg+1
        unsigned y1 = cvtpk(cy[2], cy[3]);
        swap2(x0, y0);  // x0 -> a0 (k 8g+0,1), y0 -> a2 (k 8g+4,5)
        swap2(x1, y1);  // x1 -> a1 (k 8g+2,3), y1 -> a3 (k 8g+6,7)
        const int4 ai = {(int)x0, (int)x1, (int)y0, (int)y1};
        const bf16x8 aA = __builtin_bit_cast(bf16x8, ai);
#pragma unroll
        for (int cn = 0; cn < 2; ++cn) {
          const bf16x8 vBf = *(const bf16x8*)(Vt + (size_t)(cn * 16 + l16) * ND +
                                              dbase + tg * 32 + lg * 8);
          eacc[mb][cn] = __builtin_amdgcn_mfma_f32_16x16x32_bf16(
              aA, vBf, eacc[mb][cn], 0, 0, 0);
        }
      }
    }
    // PV touches no LDS; buffers protected by the s0/s1 barriers.
  }

  // ---- epilogue: write partials (slot = dch) ----
#pragma unroll
  for (int mb = 0; mb < 2; ++mb)
#pragma unroll
    for (int cn = 0; cn < 2; ++cn)
#pragma unroll
      for (int r = 0; r < 4; ++r) {
        const int row = rowbase + mb * 16 + lg * 4 + r;
        ep[((size_t)dch * NQ + row) * 32 + cn * 16 + l16] = eacc[mb][cn][r];
      }
}

// ---------------- reduce 16 partial slots -> d_out -------------------------
__global__ __launch_bounds__(256) void reduce_kernel(const float* __restrict__ ep,
                                                     float* __restrict__ out) {
  const int g = blockIdx.x * 256 + threadIdx.x;  // 8192*32
  const int q = g >> 5, c = g & 31;
  if (c < NC) {
    float s = 0.f;
#pragma unroll
    for (int k = 0; k < NSLOT; ++k) s += ep[((size_t)k * NQ + q) * 32 + c];
    out[(size_t)q * NC + c] = s;
  } else if (c == NC) {  // ones-column == intensity
    float s = 0.f;
#pragma unroll
    for (int k = 0; k < NSLOT; ++k) s += ep[((size_t)k * NQ + q) * 32 + NC];
    out[(size_t)NQ * NC + q] = s;
  }
}

extern "C" void kernel_launch(void* const* d_in, const int* in_sizes, int n_in,
                              void* d_out, int out_size, void* d_ws, size_t ws_size,
                              hipStream_t stream) {
  const float* feat = (const float*)d_in[0];  // [8192][256]
  const float* exf  = (const float*)d_in[1];  // [16384][256]
  const float* exc  = (const float*)d_in[2];  // [16384][28]
  float* out = (float*)d_out;
  char* ws = (char*)d_ws;
  // ws layout: qn 4MB | kn 8MB | vt 1MB | ep 16MB  (~29MB)
  u16* qn = (u16*)ws;
  u16* kn = (u16*)(ws + 4194304);
  u16* vt = (u16*)(ws + 12582912);
  float* ep = (float*)(ws + 13631488);

  norm_kernel<<<dim3(NQ / 4), dim3(256), 0, stream>>>(feat, qn, NQ);
  norm_kernel<<<dim3(ND / 4), dim3(256), 0, stream>>>(exf, kn, ND);
  vt_kernel<<<dim3(ND / 256), dim3(256), 0, stream>>>(exc, vt);
  fused_kernel<<<dim3(1024), dim3(256), 0, stream>>>(qn, kn, vt, ep);
  reduce_kernel<<<dim3(NQ * 32 / 256), dim3(256), 0, stream>>>(ep, out);
}

// Round 14
// 97.408 us; speedup vs baseline: 1.4104x; 1.0145x over previous
//
#include <hip/hip_runtime.h>
#include <stdint.h>

// minerva2: echo = (F̂ Ê^T)^3 @ V, intensity = rowsum((F̂ Ê^T)^3)
// R14 = R13 geometry (64-row D-tiles, sacc[2][4], 2x16KB bufs, 3 waves/SIMD)
// with R12's EXACT proven-zero-conflict LDS layout: each 32-k step in its own
// [64d][64B] sub-slab, stored chunk p at row R = logical p ^ ((R>>1)&3),
// read chunk = lg ^ ((l16>>1)&3).

typedef unsigned short u16;
typedef __bf16 bf16x8 __attribute__((ext_vector_type(8)));
typedef float f32x4 __attribute__((ext_vector_type(4)));
typedef unsigned short u16x4 __attribute__((ext_vector_type(4)));

#define NQ 8192
#define ND 16384
#define NH 256
#define NC 28
#define DCHUNK 1024
#define NDT 16       // 64-row D-tiles per chunk
#define NSLOT 16     // partial slots = 16 D-chunks

__device__ __forceinline__ u16 f2bf(float f) {
  unsigned u = __builtin_bit_cast(unsigned, f);
  u += 0x7fffu + ((u >> 16) & 1u);   // RNE
  return (u16)(u >> 16);
}

__device__ __forceinline__ unsigned cvtpk(float lo, float hi) {
  unsigned r;
  asm("v_cvt_pk_bf16_f32 %0, %1, %2" : "=v"(r) : "v"(lo), "v"(hi));
  return r;  // low16 = bf16(lo), high16 = bf16(hi)  (RNE)
}

// After: x = [x.r0, x.r2, y.r0, y.r2] (by 16-lane row), y = [x.r1, x.r3, y.r1, y.r3]
__device__ __forceinline__ void swap2(unsigned& x, unsigned& y) {
  asm("v_permlane32_swap_b32 %0, %1" : "+v"(x), "+v"(y));  // x.r23 <-> y.r01
  asm("v_permlane16_swap_b32 %0, %1" : "+v"(x), "+v"(y));  // x.r1<->y.r0, x.r3<->y.r2
}

__device__ __forceinline__ void gload16(const void* g, void* l) {
  // async global->LDS, 16B/lane; LDS dest = wave-uniform base + lane*16
  __builtin_amdgcn_global_load_lds(
      (__attribute__((address_space(1))) void*)g,
      (__attribute__((address_space(3))) void*)l, 16, 0, 0);
}

// ---------------- normalize rows of [rows][256] f32 -> bf16 ----------------
__global__ __launch_bounds__(256) void norm_kernel(const float* __restrict__ in,
                                                   u16* __restrict__ out, int rows) {
  const int wid = threadIdx.x >> 6, lane = threadIdx.x & 63;
  const int row = blockIdx.x * 4 + wid;
  if (row >= rows) return;
  const float4* p = (const float4*)(in + (size_t)row * NH);
  float4 v = p[lane];
  float ss = v.x * v.x + v.y * v.y + v.z * v.z + v.w * v.w;
#pragma unroll
  for (int m = 1; m <= 32; m <<= 1) ss += __shfl_xor(ss, m, 64);
  const float sc = 1.0f / fmaxf(sqrtf(ss), 1e-12f);  // matches F.normalize eps
  u16x4 o;
  o.x = f2bf(v.x * sc); o.y = f2bf(v.y * sc);
  o.z = f2bf(v.z * sc); o.w = f2bf(v.w * sc);
  *(u16x4*)(out + (size_t)row * NH + lane * 4) = o;
}

// ---- V [16384][28] f32 -> Vt [32][16384] bf16; col 28 = 1.0 (intensity) ---
__global__ __launch_bounds__(256) void vt_kernel(const float* __restrict__ V,
                                                 u16* __restrict__ Vt) {
  const int d = blockIdx.x * 256 + threadIdx.x;  // 16384
#pragma unroll
  for (int c = 0; c < NC; ++c) Vt[(size_t)c * ND + d] = f2bf(V[(size_t)d * NC + c]);
  Vt[(size_t)28 * ND + d] = 0x3F80;  // bf16 1.0 -> echo col 28 == intensity
  Vt[(size_t)29 * ND + d] = 0;
  Vt[(size_t)30 * ND + d] = 0;
  Vt[(size_t)31 * ND + d] = 0;
}

// ---------------- fused main kernel ----------------------------------------
// grid 1024: dch = bid&15 (XCD-local), ntile = bid>>4. 4 waves, 1x4 over q:
// wave w owns q-rows [ntile*128+w*32, +32) x 64 d-rows per tile.
// Q (all H) in registers. LDS 32KB = 2 bufs of [4 k2][64 d][64B] (16KB each).
// Sub-slab swizzle (R12-proven): stored chunk p at row R = logical p^((R>>1)&3).
__global__ __launch_bounds__(256, 3) void fused_kernel(
    const u16* __restrict__ Qn, const u16* __restrict__ Kn,
    const u16* __restrict__ Vt, float* __restrict__ ep) {
  __shared__ alignas(16) char smem[32768];
  const int tid = threadIdx.x;
  const int wid = tid >> 6;
  const int lane = tid & 63;
  const int l16 = lane & 15;
  const int lg = lane >> 4;
  const int dch = blockIdx.x & 15;
  const int ntile = blockIdx.x >> 4;
  const int rowbase = ntile * 128 + wid * 32;

  // ---- Q fragments, all H, in registers (MFMA B-operand) ----
  bf16x8 qA[2][8];
#pragma unroll
  for (int mb = 0; mb < 2; ++mb)
#pragma unroll
    for (int ks = 0; ks < 8; ++ks)
      qA[mb][ks] = *(const bf16x8*)(Qn + (size_t)(rowbase + mb * 16 + l16) * NH +
                                    ks * 32 + lg * 8);

  f32x4 eacc[2][2];
#pragma unroll
  for (int mb = 0; mb < 2; ++mb) {
    eacc[mb][0] = f32x4{0.f, 0.f, 0.f, 0.f};
    eacc[mb][1] = f32x4{0.f, 0.f, 0.f, 0.f};
  }
  f32x4 sacc[2][4];

  const u16* kc = Kn + (size_t)dch * DCHUNK * NH;
  // staging decomposition (thread tid stages, for each k2=r: row d, chunk c):
  //   d = (tid>>6)*16 + ((tid>>2)&15)   (LDS dest: wid*1024 + lane*16 within 4KB)
  //   stored chunk = tid&3, logical chunk c = (tid&3) ^ ((d>>1)&3)
  //                = (tid&3) ^ ((tid>>3)&3)   [wid*16 contributes 0 mod 4]
  const int srow = (tid >> 6) * 16 + ((tid >> 2) & 15);
  const u16* kb = kc + (size_t)srow * NH + ((tid & 3) ^ ((tid >> 3) & 3)) * 8;

  // stage one [64d][128k] half-tile -> buf as 4 sub-slabs [64d][64B]
  // src0 = kb + tile/half element offset; sub-slab r covers k = r*32..r*32+31
  auto stage = [&](int buf, const u16* src0) {
#pragma unroll
    for (int r = 0; r < 4; ++r)
      gload16(src0 + r * 32,
              smem + buf * 16384 + r * 4096 + wid * 1024);
  };

  const int rsw = (l16 >> 1) & 3;  // (row>>1)&3 for row = nb*16 + l16

  // compute one staged half h (buf): 4 k2-steps of 32k, 8 MFMA each (D = S^T)
  auto compute = [&](int buf, int h) {
    const char* kbuf = smem + buf * 16384;
#pragma unroll
    for (int k2 = 0; k2 < 4; ++k2) {
      bf16x8 B[4];
#pragma unroll
      for (int nb = 0; nb < 4; ++nb)
        B[nb] = *(const bf16x8*)(kbuf + k2 * 4096 + (nb * 16 + l16) * 64 +
                                 ((lg ^ rsw) << 4));
#pragma unroll
      for (int mb = 0; mb < 2; ++mb)
#pragma unroll
        for (int nb = 0; nb < 4; ++nb)
          sacc[mb][nb] = __builtin_amdgcn_mfma_f32_16x16x32_bf16(
              B[nb], qA[mb][h * 4 + k2], sacc[mb][nb], 0, 0, 0);
    }
  };

  // prologue: tile 0 half 0 -> buf 0
  stage(0, kb);
  __syncthreads();

  for (int t = 0; t < NDT; ++t) {
    const size_t toff = (size_t)t * 64 * NH;
#pragma unroll
    for (int mb = 0; mb < 2; ++mb)
#pragma unroll
      for (int nb = 0; nb < 4; ++nb) sacc[mb][nb] = f32x4{0.f, 0.f, 0.f, 0.f};

    // s0: stage half1 -> buf1, compute half0 (buf0)
    stage(1, kb + toff + 128);
    compute(0, 0);
    __syncthreads();
    // s1: stage next tile half0 -> buf0, compute half1 (buf1)
    if (t < NDT - 1) stage(0, kb + toff + 64 * NH);
    compute(1, 1);
    __syncthreads();

    // ---- cube (fp32) -> bf16 pack -> permlane transpose -> PV MFMA ----
    // sacc[mb][nb]: q = l16, d(in tile) = nb*16 + lg*4 + r.
    const int dbase = dch * DCHUNK + t * 64;
#pragma unroll
    for (int mb = 0; mb < 2; ++mb) {
#pragma unroll
      for (int tg = 0; tg < 2; ++tg) {
        f32x4 sx = sacc[mb][2 * tg];
        f32x4 sy = sacc[mb][2 * tg + 1];
        f32x4 cx = sx * sx * sx;
        f32x4 cy = sy * sy * sy;
        unsigned x0 = cvtpk(cx[0], cx[1]);  // d = 4lg+0,1   (nb = 2tg)
        unsigned x1 = cvtpk(cx[2], cx[3]);  // d = 4lg+2,3
        unsigned y0 = cvtpk(cy[0], cy[1]);  // same, nb = 2tg+1
        unsigned y1 = cvtpk(cy[2], cy[3]);
        swap2(x0, y0);  // x0 -> a0 (k 8g+0,1), y0 -> a2 (k 8g+4,5)
        swap2(x1, y1);  // x1 -> a1 (k 8g+2,3), y1 -> a3 (k 8g+6,7)
        const int4 ai = {(int)x0, (int)x1, (int)y0, (int)y1};
        const bf16x8 aA = __builtin_bit_cast(bf16x8, ai);
#pragma unroll
        for (int cn = 0; cn < 2; ++cn) {
          const bf16x8 vBf = *(const bf16x8*)(Vt + (size_t)(cn * 16 + l16) * ND +
                                              dbase + tg * 32 + lg * 8);
          eacc[mb][cn] = __builtin_amdgcn_mfma_f32_16x16x32_bf16(
              aA, vBf, eacc[mb][cn], 0, 0, 0);
        }
      }
    }
    // PV touches no LDS; buffers protected by the s0/s1 barriers.
  }

  // ---- epilogue: write partials (slot = dch) ----
#pragma unroll
  for (int mb = 0; mb < 2; ++mb)
#pragma unroll
    for (int cn = 0; cn < 2; ++cn)
#pragma unroll
      for (int r = 0; r < 4; ++r) {
        const int row = rowbase + mb * 16 + lg * 4 + r;
        ep[((size_t)dch * NQ + row) * 32 + cn * 16 + l16] = eacc[mb][cn][r];
      }
}

// ---------------- reduce 16 partial slots -> d_out -------------------------
__global__ __launch_bounds__(256) void reduce_kernel(const float* __restrict__ ep,
                                                     float* __restrict__ out) {
  const int g = blockIdx.x * 256 + threadIdx.x;  // 8192*32
  const int q = g >> 5, c = g & 31;
  if (c < NC) {
    float s = 0.f;
#pragma unroll
    for (int k = 0; k < NSLOT; ++k) s += ep[((size_t)k * NQ + q) * 32 + c];
    out[(size_t)q * NC + c] = s;
  } else if (c == NC) {  // ones-column == intensity
    float s = 0.f;
#pragma unroll
    for (int k = 0; k < NSLOT; ++k) s += ep[((size_t)k * NQ + q) * 32 + NC];
    out[(size_t)NQ * NC + q] = s;
  }
}

extern "C" void kernel_launch(void* const* d_in, const int* in_sizes, int n_in,
                              void* d_out, int out_size, void* d_ws, size_t ws_size,
                              hipStream_t stream) {
  const float* feat = (const float*)d_in[0];  // [8192][256]
  const float* exf  = (const float*)d_in[1];  // [16384][256]
  const float* exc  = (const float*)d_in[2];  // [16384][28]
  float* out = (float*)d_out;
  char* ws = (char*)d_ws;
  // ws layout: qn 4MB | kn 8MB | vt 1MB | ep 16MB  (~29MB)
  u16* qn = (u16*)ws;
  u16* kn = (u16*)(ws + 4194304);
  u16* vt = (u16*)(ws + 12582912);
  float* ep = (float*)(ws + 13631488);

  norm_kernel<<<dim3(NQ / 4), dim3(256), 0, stream>>>(feat, qn, NQ);
  norm_kernel<<<dim3(ND / 4), dim3(256), 0, stream>>>(exf, kn, ND);
  vt_kernel<<<dim3(ND / 256), dim3(256), 0, stream>>>(exc, vt);
  fused_kernel<<<dim3(1024), dim3(256), 0, stream>>>(qn, kn, vt, ep);
  reduce_kernel<<<dim3(NQ * 32 / 256), dim3(256), 0, stream>>>(ep, out);
}